// Round 2
// 400.676 us; speedup vs baseline: 1.0006x; 1.0006x over previous
//
#include <hip/hip_runtime.h>
#include <math.h>

// Problem constants (from reference):
#define NROWS 1000000
#define NF    64      // N_FIXED
#define BB    5000    // B
#define LLg   10      // L
#define TTg   25      // T
#define KKg   8       // K

// ws layout (in floats):
//   [1024, 1024+T*B*L*K)  u table (T,B,L,K)  40 MB
#define WS_U 1024

// Native clang vector types: __builtin_nontemporal_load/store require
// scalar or ext_vector_type pointers (HIP_vector_type structs are rejected).
typedef float f32x4 __attribute__((ext_vector_type(4)));
typedef int   i32x2 __attribute__((ext_vector_type(2)));

// ---------------------------------------------------------------------------
// Per-block prep into LDS: rho = tanh(raw_rho); d = diag(chol(Sigma[k])).
// Redundant per block (80 tanh + 8 10x10 Choleskys) -- cheaper than a
// separate 1-block kernel launch + ws round-trip. Chol scratch lives in LDS
// (packed lower-tri, 55 floats/k) so it never inflates the kernel's VGPRs.
// ---------------------------------------------------------------------------
__device__ __forceinline__ void prep_lds(const float* __restrict__ raw_rho,
                                         const float* __restrict__ Sigma,
                                         float* s_rho, float* s_d,
                                         float (*s_L)[55]) {
    const int tid = threadIdx.x;
    if (tid < LLg * KKg) s_rho[tid] = tanhf(raw_rho[tid]);
    if (tid < KKg) {
        const int k = tid;
        const float* S = Sigma + k * LLg * LLg;
        float* Lt = s_L[k];
        for (int i = 0; i < LLg; ++i) {
            const int ib = i * (i + 1) / 2;
            for (int j = 0; j <= i; ++j) {
                const int jb = j * (j + 1) / 2;
                float s = S[i * LLg + j];
                for (int m = 0; m < j; ++m) s -= Lt[ib + m] * Lt[jb + m];
                if (i == j) {
                    const float v = sqrtf(s);
                    Lt[ib + j] = v;
                    s_d[i * KKg + k] = v;
                } else {
                    Lt[ib + j] = s / Lt[jb + j];
                }
            }
        }
    }
}

// ---------------------------------------------------------------------------
// u table: AR(1) recurrence, one thread per (b,l,k). All 25 eps loads are
// issued up-front (addresses are independent of the recurrence) so the
// dependent rho*u chain never waits on HBM. Stores coalesced per t.
// eps is read exactly once -> nontemporal (don't thrash L2).
// ---------------------------------------------------------------------------
__global__ __launch_bounds__(256) void u_kernel(const float* __restrict__ eps,
                                                const float* __restrict__ raw_rho,
                                                const float* __restrict__ Sigma,
                                                float* __restrict__ u) {
    __shared__ float s_rho[LLg * KKg];
    __shared__ float s_d[LLg * KKg];
    __shared__ float s_L[KKg][55];
    prep_lds(raw_rho, Sigma, s_rho, s_d, s_L);
    __syncthreads();

    const int tid = blockIdx.x * blockDim.x + threadIdx.x;
    if (tid >= BB * LLg * KKg) return;
    const int k = tid % KKg;
    const int l = (tid / KKg) % LLg;
    const int b = tid / (KKg * LLg);
    const float rho = s_rho[l * KKg + k];
    const float dv  = s_d[l * KKg + k];
    const float* ep = eps + ((size_t)(b * LLg + l) * TTg) * KKg + k;
    float* up = u + (size_t)(b * LLg + l) * KKg + k;   // t=0 slot
    const size_t ustride = (size_t)BB * LLg * KKg;     // stride in t

    float ev[TTg];
#pragma unroll
    for (int t = 0; t < TTg; ++t)
        ev[t] = __builtin_nontemporal_load(ep + (size_t)t * KKg);

    float uv = ev[0];
    up[0] = uv;
#pragma unroll
    for (int t = 1; t < TTg; ++t) {
        uv = rho * uv + dv * ev[t];
        up[(size_t)t * ustride] = uv;
    }
}

// ---------------------------------------------------------------------------
// Main: out[row,k] = dot(X[row,:], beta[:,k]) + u[sea,bat,lea,k]
//
// f-split decomposition (R2's k-split was vmem-issue-bound). Lane j of an
// 8-lane group reads ONLY X[row, j*8 .. j*8+8) (coalesced across the wave),
// holds beta[j*8..j*8+8)][0..8) in 64 VGPRs (one-shot from bank-conflict-
// padded LDS), accumulates partials for all 8 k, then a 3-stage __shfl_xor
// reduce-scatter leaves the full sum for k=j on lane j -- matching the
// coalesced u-gather and out store. Each group does 2 adjacent rows.
//
// X / ids stream through exactly once -> nontemporal loads; out -> nontemporal
// store. This keeps L2 available for the random u-table gather (40 MB table
// vs 32 MB aggregate L2 -- streaming 256 MB of X through L2 evicts it).
// ---------------------------------------------------------------------------
template <bool USE_TABLE>
__global__ __launch_bounds__(256) void main_kernel(
    const float* __restrict__ X,
    const int*   __restrict__ bat,
    const int*   __restrict__ lea,
    const int*   __restrict__ sea,
    const float* __restrict__ beta,
    const float* __restrict__ u_table,
    const float* __restrict__ raw_rho,
    const float* __restrict__ Sigma,
    const float* __restrict__ eps,
    float*       __restrict__ out)
{
    // LDS beta, padded: slice j (f = j*8+ff) at stride 68 floats so the 8
    // lanes of a group hit disjoint bank quads (68%32=4 -> banks j*4..j*4+3).
    __shared__ float sbeta[8 * 68];
    __shared__ float s_rho[LLg * KKg];   // fallback path only
    __shared__ float s_d[LLg * KKg];
    __shared__ float s_L[KKg][55];

    if (!USE_TABLE)
        prep_lds(raw_rho, Sigma, s_rho, s_d, s_L);

    for (int i = threadIdx.x; i < NF * KKg; i += blockDim.x) {
        const int f = i >> 3, k = i & 7;
        sbeta[(f >> 3) * 68 + (f & 7) * 8 + k] = beta[i];
    }
    __syncthreads();

    const int gt   = blockIdx.x * blockDim.x + threadIdx.x;
    const int j    = gt & 7;          // lane-in-group: f-slice owner AND final k owner
    const int g    = gt >> 3;         // group id, 0..499999
    const int row0 = g * 2;

    // --- ids for both rows (group-uniform 8 B loads, streamed once) ---
    const i32x2 bb = __builtin_nontemporal_load((const i32x2*)(bat + row0));
    const i32x2 ll = __builtin_nontemporal_load((const i32x2*)(lea + row0));
    const i32x2 tt = __builtin_nontemporal_load((const i32x2*)(sea + row0));

    // --- X slices (coalesced: group reads contiguous 256 B per row) ---
    const float* xr0p = X + (size_t)row0 * NF + j * 8;
    const float* xr1p = X + (size_t)(row0 + 1) * NF + j * 8;
    const f32x4 x0a = __builtin_nontemporal_load((const f32x4*)xr0p);
    const f32x4 x0b = __builtin_nontemporal_load((const f32x4*)xr0p + 1);
    const f32x4 x1a = __builtin_nontemporal_load((const f32x4*)xr1p);
    const f32x4 x1b = __builtin_nontemporal_load((const f32x4*)xr1p + 1);
    float xr0[8], xr1[8];
#pragma unroll
    for (int i = 0; i < 4; ++i) {
        xr0[i] = x0a[i]; xr0[i + 4] = x0b[i];
        xr1[i] = x1a[i]; xr1[i + 4] = x1b[i];
    }

    // --- u values for k=j (coalesced 32 B per group; wants to hit L2) ---
    float uv0, uv1;
    if (USE_TABLE) {
        uv0 = u_table[(((size_t)tt.x * BB + bb.x) * LLg + ll.x) * KKg + j];
        uv1 = u_table[(((size_t)tt.y * BB + bb.y) * LLg + ll.y) * KKg + j];
    } else {
        const float rho0 = s_rho[ll.x * KKg + j];
        const float dv0  = s_d[ll.x * KKg + j];
        const float* e0  = eps + ((size_t)(bb.x * LLg + ll.x) * TTg) * KKg + j;
        uv0 = e0[0];
        for (int s = 1; s <= tt.x; ++s) uv0 = rho0 * uv0 + dv0 * e0[(size_t)s * KKg];
        const float rho1 = s_rho[ll.y * KKg + j];
        const float dv1  = s_d[ll.y * KKg + j];
        const float* e1  = eps + ((size_t)(bb.y * LLg + ll.y) * TTg) * KKg + j;
        uv1 = e1[0];
        for (int s = 1; s <= tt.y; ++s) uv1 = rho1 * uv1 + dv1 * e1[(size_t)s * KKg];
    }

    // --- beta slice -> 64 VGPRs (one-shot, conflict-free ds_read_b128) ---
    float bv[8][8];   // [ff][k]
#pragma unroll
    for (int ff = 0; ff < 8; ++ff) {
        const float4* p = (const float4*)&sbeta[j * 68 + ff * 8];
        const float4 u0 = p[0], u1 = p[1];
        bv[ff][0] = u0.x; bv[ff][1] = u0.y; bv[ff][2] = u0.z; bv[ff][3] = u0.w;
        bv[ff][4] = u1.x; bv[ff][5] = u1.y; bv[ff][6] = u1.z; bv[ff][7] = u1.w;
    }

    // --- partial dot products: 8 f x 8 k per lane, both rows ---
    float p0[8], p1[8];
#pragma unroll
    for (int k = 0; k < 8; ++k) { p0[k] = 0.f; p1[k] = 0.f; }
#pragma unroll
    for (int ff = 0; ff < 8; ++ff) {
#pragma unroll
        for (int k = 0; k < 8; ++k) {
            p0[k] += xr0[ff] * bv[ff][k];
            p1[k] += xr1[ff] * bv[ff][k];
        }
    }

    // --- reduce-scatter across the 8-lane group: after stages 4,2,1 lane j
    //     holds the full sum for k=j (k bits chosen to match j's bits) ---
#pragma unroll
    for (int i = 0; i < 4; ++i) {
        const float s0 = (j & 4) ? p0[i] : p0[i + 4];
        const float s1 = (j & 4) ? p1[i] : p1[i + 4];
        const float k0 = (j & 4) ? p0[i + 4] : p0[i];
        const float k1 = (j & 4) ? p1[i + 4] : p1[i];
        p0[i] = k0 + __shfl_xor(s0, 4);
        p1[i] = k1 + __shfl_xor(s1, 4);
    }
#pragma unroll
    for (int i = 0; i < 2; ++i) {
        const float s0 = (j & 2) ? p0[i] : p0[i + 2];
        const float s1 = (j & 2) ? p1[i] : p1[i + 2];
        const float k0 = (j & 2) ? p0[i + 2] : p0[i];
        const float k1 = (j & 2) ? p1[i + 2] : p1[i];
        p0[i] = k0 + __shfl_xor(s0, 2);
        p1[i] = k1 + __shfl_xor(s1, 2);
    }
    {
        const float s0 = (j & 1) ? p0[0] : p0[1];
        const float s1 = (j & 1) ? p1[0] : p1[1];
        const float k0 = (j & 1) ? p0[1] : p0[0];
        const float k1 = (j & 1) ? p1[1] : p1[0];
        p0[0] = k0 + __shfl_xor(s0, 1);
        p1[0] = k1 + __shfl_xor(s1, 1);
    }

    // --- store (32 B contiguous per group, streamed) ---
    __builtin_nontemporal_store(p0[0] + uv0, out + (size_t)row0 * KKg + j);
    __builtin_nontemporal_store(p1[0] + uv1, out + (size_t)(row0 + 1) * KKg + j);
}

extern "C" void kernel_launch(void* const* d_in, const int* in_sizes, int n_in,
                              void* d_out, int out_size, void* d_ws, size_t ws_size,
                              hipStream_t stream) {
    const float* X       = (const float*)d_in[0];
    const int*   bat     = (const int*)  d_in[1];
    const int*   lea     = (const int*)  d_in[2];
    const int*   sea     = (const int*)  d_in[3];
    const float* beta    = (const float*)d_in[4];
    const float* raw_rho = (const float*)d_in[5];
    const float* Sigma   = (const float*)d_in[6];
    const float* eps     = (const float*)d_in[7];
    float* out = (float*)d_out;
    float* ws  = (float*)d_ws;
    float* u   = ws + WS_U;

    const size_t need_bytes = ((size_t)WS_U + (size_t)TTg * BB * LLg * KKg) * sizeof(float);
    const bool use_table = ws_size >= need_bytes;   // constant per harness -> graph-safe

    const int nthreads = (NROWS / 2) * KKg;         // 4M
    const int nblocks  = nthreads / 256;            // 15625, exact cover

    if (use_table) {
        u_kernel<<<(BB * LLg * KKg + 255) / 256, 256, 0, stream>>>(eps, raw_rho, Sigma, u);
        main_kernel<true><<<nblocks, 256, 0, stream>>>(X, bat, lea, sea, beta, u,
                                                       raw_rho, Sigma, eps, out);
    } else {
        main_kernel<false><<<nblocks, 256, 0, stream>>>(X, bat, lea, sea, beta, u,
                                                        raw_rho, Sigma, eps, out);
    }
}